// Round 7
// baseline (7025.381 us; speedup 1.0000x reference)
//
#include <hip/hip_runtime.h>
#include <hip/hip_bf16.h>
#include <stdint.h>

// Neural CDE, B=256 T=512 D=64 H=128 W=256.
// Round 7: staggered dual-group persistent kernel.
//  - 16 groups of 16 batch rows; WG pair p serves groups 2p (set A) and 2p+1 (set B).
//  - 256 WGs = 8 pairs x 32 WGs; each WG owns 256 HD cols for BOTH sets; 1 WG/CU.
//  - per macro-iter: process set A then set B; each set's publish->poll gap is
//    covered by the other set's compute => exchange latency hidden.
//  - w2 chunk LDS-resident (128 KB, shared by both sets); all set buffers shared.
//  - tagged bf16 push-exchange per set (relaxed agent atomics, 2-slot, ABA-safe).
// dt = 1, frac = 0 for k<=510 => deriv = coeffs_b[:,k]; k=511 => b+2c+3d at idx 510.

#define BB 256
#define DD 64
#define HH 128
#define WW 256
#define HD 8192
#define TSTEPS 512
#define PAD_Y 136   // bf16 row stride for yb
#define PAD_G 264   // bf16 row stride for g0/g1

#define SM_W2   0        // 131072 B
#define SM_YB   131072   // 16*136*2 = 4352 B
#define SM_G0   135424   // 16*264*2 = 8448 B
#define SM_G1   143872   // 8448 B
#define SM_PBUF 152320   // 8*16*4 = 512 B
#define SM_TOT  152832

typedef __bf16 bf16x8 __attribute__((ext_vector_type(8)));
typedef __bf16 bf16x4 __attribute__((ext_vector_type(4)));
typedef float f32x4 __attribute__((ext_vector_type(4)));

__device__ __forceinline__ float softplus_f(float x) {
  return (x > 15.f) ? x : __logf(1.f + __expf(x));
}
__device__ __forceinline__ float tanh_f(float x) {
  float e = __expf(2.f * x);
  return 1.f - 2.f / (e + 1.f);
}
__device__ __forceinline__ uint32_t aload(const uint32_t* p) {
  return __hip_atomic_load(p, __ATOMIC_RELAXED, __HIP_MEMORY_SCOPE_AGENT);
}
__device__ __forceinline__ void publish_y(uint32_t* slot, int idx, float val, uint32_t tag) {
  unsigned short ub = __builtin_bit_cast(unsigned short, (__bf16)val);
  __hip_atomic_store(&slot[idx], (tag << 16) | (uint32_t)ub,
                     __ATOMIC_RELAXED, __HIP_MEMORY_SCOPE_AGENT);
}

__global__ void prep_kernel(const float* __restrict__ w0, const float* __restrict__ w1,
                            const float* __restrict__ w2,
                            __bf16* __restrict__ w0b, __bf16* __restrict__ w1b,
                            __bf16* __restrict__ w2b) {
  int stride = gridDim.x * blockDim.x;
  int i0 = blockIdx.x * blockDim.x + threadIdx.x;
  for (int i = i0; i < WW * HH; i += stride) w0b[i] = (__bf16)w0[i];
  for (int i = i0; i < WW * WW; i += stride) w1b[i] = (__bf16)w1[i];
  for (int i = i0; i < HD * WW; i += stride) w2b[i] = (__bf16)w2[i];
}

__global__ __launch_bounds__(256) void init_kernel(
    const float* __restrict__ ca, const float* __restrict__ iw0, const float* __restrict__ ib0,
    const float* __restrict__ iw1, const float* __restrict__ ib1,
    const float* __restrict__ iw2, const float* __restrict__ ib2,
    float* __restrict__ y0) {
  __shared__ float x0[DD];
  __shared__ float h0[WW];
  __shared__ float h1[WW];
  int b = blockIdx.x, t = threadIdx.x;
  if (t < DD) x0[t] = ca[((size_t)b * 511) * DD + t];
  __syncthreads();
  float a = ib0[t];
  for (int d = 0; d < DD; ++d) a = fmaf(x0[d], iw0[t * DD + d], a);
  h0[t] = fmaxf(a, 0.f);
  __syncthreads();
  a = ib1[t];
  for (int d = 0; d < WW; ++d) a = fmaf(h0[d], iw1[t * WW + d], a);
  h1[t] = fmaxf(a, 0.f);
  __syncthreads();
  if (t < HH) {
    a = ib2[t];
    for (int d = 0; d < WW; ++d) a = fmaf(h1[d], iw2[t * WW + d], a);
    y0[b * HH + t] = a;
  }
}

// Persistent step kernel: 256 WGs x 512 threads, macro-loop k=0..511, 2 sets per iter.
__global__ __attribute__((amdgpu_flat_work_group_size(512, 512), amdgpu_waves_per_eu(2, 2)))
void step_persist(
    const __bf16* __restrict__ w0b, const __bf16* __restrict__ w1b, const __bf16* __restrict__ w2b,
    const float* __restrict__ fb0, const float* __restrict__ fb1, const float* __restrict__ fb2,
    const float* __restrict__ cbp, const float* __restrict__ ccp, const float* __restrict__ cdp,
    float* __restrict__ yA, uint32_t* __restrict__ pk)
{
  extern __shared__ __align__(16) char smem[];
  __bf16* w2l = (__bf16*)(smem + SM_W2);    // [kq=kb*4+lq][col(256)][8] = 128 KB
  __bf16* yb  = (__bf16*)(smem + SM_YB);    // 16 x PAD_Y
  __bf16* g0s = (__bf16*)(smem + SM_G0);    // 16 x PAD_G
  __bf16* g1s = (__bf16*)(smem + SM_G1);    // 16 x PAD_G
  float* pbuf = (float*)(smem + SM_PBUF);   // 8 x 16

  const int tid = threadIdx.x;
  const int wv = tid >> 6;
  const int l = tid & 63;
  const int l16 = l & 15;
  const int lq = l >> 4;

  const int wid = blockIdx.x;
  const int p = wid >> 5;      // pair index: groups 2p (set A), 2p+1 (set B)
  const int j = wid & 31;
  const int rb0 = p * 32;      // set s rows: rb0 + 16*s .. +16
  const int c0 = j * 256;      // HD col base (shared by both sets)

  // ---- one-time: stage this WG's w2 chunk into LDS, layout [kq][col][8]
  for (int blk = tid; blk < 8192; blk += 512) {
    int kq = blk >> 8, col = blk & 255;
    int kb = kq >> 2, lq2 = kq & 3;
    *(bf16x8*)&w2l[(size_t)blk * 8] =
        *(const bf16x8*)&w2b[(size_t)(c0 + col) * WW + kb * 32 + lq2 * 8];
  }
  const int w2base = lq * 2048 + (wv * 32 + l16) * 8;

  // ---- loop-invariant biases (col-quad layout, reg dim)
  f32x4 b0r[2], b1r[2], b2r[2];
  #pragma unroll
  for (int c = 0; c < 2; ++c) {
    b0r[c] = *(const f32x4*)&fb0[wv * 32 + c * 16 + lq * 4];
    b1r[c] = *(const f32x4*)&fb1[wv * 32 + c * 16 + lq * 4];
    b2r[c] = *(const f32x4*)&fb2[c0 + wv * 32 + c * 16 + lq * 4];
  }

  // ---- per-set deriv base offsets (row = rbs + l16, d-slice (wv&1)*32 + lq*4)
  size_t cb2[2];
  #pragma unroll
  for (int s = 0; s < 2; ++s)
    cb2[s] = ((size_t)(rb0 + 16 * s + l16) * 511) * DD + (wv & 1) * 32 + lq * 4;

  // ---- register-resident f32 state: tid<64 owns (row rbs+(tid&15), h = 4j+(tid>>4))
  float yreg[2] = {0.f, 0.f};
  int myidx[2] = {0, 0};
  if (tid < 64) {
    int r = tid & 15, hl = tid >> 4;
    #pragma unroll
    for (int s = 0; s < 2; ++s) {
      myidx[s] = (rb0 + 16 * s + r) * HH + (4 * j + hl);
      yreg[s] = yA[myidx[s]];
      publish_y(pk, myidx[s], yreg[s], 1u);   // S_0 -> slot 0, tag 1
    }
  }
  __syncthreads();   // w2l staged before first use

  for (int k = 0; k < TSTEPS; ++k) {
    const uint32_t want = (uint32_t)(k + 1);
    const uint32_t* src = pk + (size_t)(k & 1) * (BB * HH);
    uint32_t* dst = pk + (size_t)((k + 1) & 1) * (BB * HH);

    #pragma unroll
    for (int s = 0; s < 2; ++s) {
      const int rbs = rb0 + 16 * s;

      // ---- prefetch w0/w1 fragments (issued before the poll; clobber stops sinking)
      bf16x8 w0f[4][2], w1f[8][2];
      #pragma unroll
      for (int c = 0; c < 2; ++c) {
        int col = wv * 32 + c * 16 + l16;
        #pragma unroll
        for (int kb = 0; kb < 4; ++kb)
          w0f[kb][c] = *(const bf16x8*)&w0b[col * HH + kb * 32 + lq * 8];
        #pragma unroll
        for (int kb = 0; kb < 8; ++kb)
          w1f[kb][c] = *(const bf16x8*)&w1b[col * WW + kb * 32 + lq * 8];
      }
      __asm__ __volatile__("" ::: "memory");

      // ---- poll this set's 16x128 y words (4 per thread)
      {
        uint32_t v[4];
        int ad[4];
        #pragma unroll
        for (int q = 0; q < 4; ++q) {
          int i = tid + q * 512;
          ad[q] = (rbs + (i >> 7)) * HH + (i & 127);
          v[q] = aload(&src[ad[q]]);
        }
        int spins = 0;
        bool allok;
        do {
          allok = true;
          #pragma unroll
          for (int q = 0; q < 4; ++q) {
            if ((v[q] >> 16) != want) {
              allok = false;
              v[q] = aload(&src[ad[q]]);
            }
          }
          if (!allok) {
            __builtin_amdgcn_s_sleep(1);
            if (++spins > (1 << 20)) break;   // structurally impossible; bail visibly
          }
        } while (!allok);
        #pragma unroll
        for (int q = 0; q < 4; ++q) {
          int i = tid + q * 512;
          yb[(i >> 7) * PAD_Y + (i & 127)] =
              __builtin_bit_cast(__bf16, (unsigned short)(v[q] & 0xFFFFu));
        }
      }

      // ---- deriv loads (f32x4 direct; consumed in gemm2, latency hidden)
      f32x4 dvv[2];
      {
        size_t ko = (size_t)((k <= 510) ? k : 510) * DD;
        #pragma unroll
        for (int c = 0; c < 2; ++c) {
          size_t off = cb2[s] + ko + c * 16;
          dvv[c] = *(const f32x4*)&cbp[off];
          if (k == 511) {
            f32x4 cc = *(const f32x4*)&ccp[off];
            f32x4 dd = *(const f32x4*)&cdp[off];
            #pragma unroll
            for (int r = 0; r < 4; ++r)
              dvv[c][r] += 2.f * cc[r] + 3.f * dd[r];
          }
        }
      }
      __syncthreads();   // A: yb ready

      // ---- gemm0 (swapped): D[w0col, brow] = w0 . y
      {
        f32x4 acc[2] = {};
        #pragma unroll
        for (int kb = 0; kb < 4; ++kb) {
          bf16x8 y0 = *(const bf16x8*)&yb[l16 * PAD_Y + kb * 32 + lq * 8];
          #pragma unroll
          for (int c = 0; c < 2; ++c)
            acc[c] = __builtin_amdgcn_mfma_f32_16x16x32_bf16(w0f[kb][c], y0, acc[c], 0, 0, 0);
        }
        #pragma unroll
        for (int c = 0; c < 2; ++c) {
          bf16x4 o;
          #pragma unroll
          for (int r = 0; r < 4; ++r)
            o[r] = (__bf16)softplus_f(acc[c][r] + b0r[c][r]);
          *(bf16x4*)&g0s[l16 * PAD_G + wv * 32 + c * 16 + lq * 4] = o;
        }
      }
      __syncthreads();   // B: g0 ready

      // ---- gemm1 (swapped): reads g0, writes g1 (separate buffers, no mid-barrier)
      {
        f32x4 acc[2] = {};
        #pragma unroll
        for (int kb = 0; kb < 8; ++kb) {
          bf16x8 a0 = *(const bf16x8*)&g0s[l16 * PAD_G + kb * 32 + lq * 8];
          #pragma unroll
          for (int c = 0; c < 2; ++c)
            acc[c] = __builtin_amdgcn_mfma_f32_16x16x32_bf16(w1f[kb][c], a0, acc[c], 0, 0, 0);
        }
        #pragma unroll
        for (int c = 0; c < 2; ++c) {
          bf16x4 o;
          #pragma unroll
          for (int r = 0; r < 4; ++r)
            o[r] = (__bf16)softplus_f(acc[c][r] + b1r[c][r]);
          *(bf16x4*)&g1s[l16 * PAD_G + wv * 32 + c * 16 + lq * 4] = o;
        }
      }
      __syncthreads();   // D: g1 ready

      // ---- gemm2 chunk (swapped, w2 from LDS) + tanh + d-contraction
      {
        f32x4 acc[2] = {};
        #pragma unroll
        for (int kb = 0; kb < 8; ++kb) {
          bf16x8 a0 = *(const bf16x8*)&g1s[l16 * PAD_G + kb * 32 + lq * 8];
          #pragma unroll
          for (int c = 0; c < 2; ++c) {
            bf16x8 wf = *(const bf16x8*)&w2l[w2base + kb * 8192 + c * 128];
            acc[c] = __builtin_amdgcn_mfma_f32_16x16x32_bf16(wf, a0, acc[c], 0, 0, 0);
          }
        }
        // lane holds: batch row = l16; d = (wv&1)*32 + c*16 + lq*4 + r
        float pp = 0.f;
        #pragma unroll
        for (int c = 0; c < 2; ++c)
          #pragma unroll
          for (int r = 0; r < 4; ++r) {
            float f = tanh_f(acc[c][r] + b2r[c][r]);
            pp = fmaf(f, dvv[c][r], pp);
          }
        pp += __shfl_xor(pp, 16);
        pp += __shfl_xor(pp, 32);
        if (l < 16) pbuf[wv * 16 + l] = pp;
      }
      __syncthreads();   // E: pbuf ready

      // ---- combine wave pairs (d halves), update register state, publish
      if (tid < 64) {
        int r = tid & 15, hl = tid >> 4;
        yreg[s] += pbuf[(2 * hl) * 16 + r] + pbuf[(2 * hl + 1) * 16 + r];
        publish_y(dst, myidx[s], yreg[s], (uint32_t)(k + 2));
      }
      // no trailing barrier: next set's first overwrite of shared buffers is
      // separated from this set's last reads by its own A/B/D barriers.
    }
  }

  if (tid < 64) {
    yA[myidx[0]] = yreg[0];
    yA[myidx[1]] = yreg[1];
  }
}

__global__ __launch_bounds__(256) void final_kernel(const float* __restrict__ y,
                                                    const float* __restrict__ lw,
                                                    const float* __restrict__ lb,
                                                    float* __restrict__ out) {
  int b = threadIdx.x;
  float a = lb[0];
  for (int h = 0; h < HH; ++h) a = fmaf(y[b * HH + h], lw[h], a);
  out[b] = 1.f / (1.f + __expf(-a));
}

extern "C" void kernel_launch(void* const* d_in, const int* in_sizes, int n_in,
                              void* d_out, int out_size, void* d_ws, size_t ws_size,
                              hipStream_t stream) {
  const float* cdp = (const float*)d_in[1];
  const float* ccp = (const float*)d_in[2];
  const float* cbp = (const float*)d_in[3];
  const float* cap = (const float*)d_in[4];
  const float* iw0 = (const float*)d_in[5];
  const float* ib0 = (const float*)d_in[6];
  const float* iw1 = (const float*)d_in[7];
  const float* ib1 = (const float*)d_in[8];
  const float* iw2 = (const float*)d_in[9];
  const float* ib2 = (const float*)d_in[10];
  const float* fw0 = (const float*)d_in[11];
  const float* fb0 = (const float*)d_in[12];
  const float* fw1 = (const float*)d_in[13];
  const float* fb1 = (const float*)d_in[14];
  const float* fw2 = (const float*)d_in[15];
  const float* fb2 = (const float*)d_in[16];
  const float* lw  = (const float*)d_in[17];
  const float* lb  = (const float*)d_in[18];

  char* ws = (char*)d_ws;
  __bf16* w0b = (__bf16*)(ws);                              // 64 KB
  __bf16* w1b = (__bf16*)(ws + 65536);                      // 128 KB
  __bf16* w2b = (__bf16*)(ws + 65536 + 131072);             // 4 MB
  float* yA = (float*)(ws + 65536 + 131072 + 4194304);      // 128 KB
  uint32_t* pk = (uint32_t*)(ws + 65536 + 131072 + 4194304 + 131072);  // 256 KB (2 slots)

  hipMemsetAsync(pk, 0, 2 * BB * HH * sizeof(uint32_t), stream);
  prep_kernel<<<512, 256, 0, stream>>>(fw0, fw1, fw2, w0b, w1b, w2b);
  init_kernel<<<BB, 256, 0, stream>>>(cap, iw0, ib0, iw1, ib1, iw2, ib2, yA);
  step_persist<<<256, 512, SM_TOT, stream>>>(w0b, w1b, w2b, fb0, fb1, fb2,
                                             cbp, ccp, cdp, yA, pk);
  final_kernel<<<1, 256, 0, stream>>>(yA, lw, lb, (float*)d_out);

  (void)in_sizes; (void)n_in; (void)out_size; (void)ws_size;
}